// Round 1
// baseline (662.375 us; speedup 1.0000x reference)
//
#include <hip/hip_runtime.h>
#include <hip/hip_bf16.h>

// ---------------- problem constants ----------------
#define T_TOK 512
#define HD    2048   // hidden
#define ID    1024   // moe intermediate
#define NE    32     // routed experts
#define TOPK  8
#define NGRP  8
#define TGRP  4
#define NSH   2
#define SCALE 2.5f

typedef __attribute__((ext_vector_type(8))) short bf16x8;
typedef __attribute__((ext_vector_type(4))) float f32x4;
typedef unsigned short u16;
typedef unsigned long long u64;

__device__ __forceinline__ u16 f2bf(float f) {
    union { float f; unsigned u; } a; a.f = f;
    unsigned r = a.u + 0x7FFFu + ((a.u >> 16) & 1u);   // RNE
    return (u16)(r >> 16);
}

__device__ __forceinline__ f32x4 mfma16(bf16x8 a, bf16x8 b, f32x4 c) {
    return __builtin_amdgcn_mfma_f32_16x16x32_bf16(a, b, c, 0, 0, 0);
}

// frag: elems 0..3 at k = 4*(lane>>4)+j, elems 4..7 at k+16 (k-blocked layout)
__device__ __forceinline__ bf16x8 ldfrag(const u16* p) {
    union { bf16x8 v; u64 h[2]; } f;
    f.h[0] = *(const u64*)(p);
    f.h[1] = *(const u64*)(p + 16);
    return f.v;
}

// ---------------- x -> bf16 ----------------
__global__ __launch_bounds__(256) void k_xconv(const float* __restrict__ x,
                                               u16* __restrict__ xb) {
    int i = (blockIdx.x * 256 + threadIdx.x) * 8;
    float4 a = *(const float4*)(x + i);
    float4 b = *(const float4*)(x + i + 4);
    union { u16 u[8]; uint4 q; } pk;
    pk.u[0] = f2bf(a.x); pk.u[1] = f2bf(a.y); pk.u[2] = f2bf(a.z); pk.u[3] = f2bf(a.w);
    pk.u[4] = f2bf(b.x); pk.u[5] = f2bf(b.y); pk.u[6] = f2bf(b.z); pk.u[7] = f2bf(b.w);
    *(uint4*)(xb + i) = pk.q;
}

// ---------------- routing: one block per token ----------------
__global__ __launch_bounds__(64) void k_route(const float* __restrict__ x,
                                              const float* __restrict__ gw,
                                              const float* __restrict__ gb,
                                              int* __restrict__ counts,
                                              int* __restrict__ tok_ids,
                                              float* __restrict__ tok_w) {
    const int t = blockIdx.x, lane = threadIdx.x;
    __shared__ float xr[HD];
    __shared__ float slog[NE], ss[NE], scb[NE], smm[NE];
    for (int i = lane; i < HD; i += 64) xr[i] = x[(size_t)t * HD + i];
    __syncthreads();
    const int e = lane >> 1, half = lane & 1;
    const float4* w4 = (const float4*)(gw + (size_t)e * HD + half * 1024);
    const float4* x4 = (const float4*)(xr + half * 1024);
    float acc = 0.f;
    for (int i = 0; i < 256; i++) {
        float4 a = x4[i], b = w4[i];
        acc += a.x * b.x + a.y * b.y + a.z * b.z + a.w * b.w;
    }
    acc += __shfl_xor(acc, 1, 64);
    if (!half) slog[e] = acc;
    __syncthreads();
    if (lane == 0) {
        for (int i = 0; i < NE; i++) {
            float s = 1.f / (1.f + __expf(-slog[i]));
            ss[i] = s; scb[i] = s + gb[i];
        }
        float gsc[NGRP];
        for (int g = 0; g < NGRP; g++) {
            float a = scb[4*g], b = scb[4*g+1], c = scb[4*g+2], d = scb[4*g+3];
            float mab = fmaxf(a,b), nab = fminf(a,b), mcd = fmaxf(c,d), ncd = fminf(c,d);
            float m2 = (mab >= mcd) ? fmaxf(nab, mcd) : fmaxf(ncd, mab);
            gsc[g] = fmaxf(mab, mcd) + m2;   // sum of top-2 in group
        }
        int gmask = 0;
        for (int it = 0; it < TGRP; it++) {   // top-4 groups, ties -> lowest idx
            float best = -1e30f; int bi = 0;
            for (int g = 0; g < NGRP; g++)
                if (!((gmask >> g) & 1) && gsc[g] > best) { best = gsc[g]; bi = g; }
            gmask |= 1 << bi;
        }
        for (int i = 0; i < NE; i++)
            smm[i] = ((gmask >> (i >> 2)) & 1) ? scb[i] : -1e30f;
        int ids[TOPK]; float wv[TOPK]; float wsum = 0.f;
        for (int k = 0; k < TOPK; k++) {      // top-8 experts, ties -> lowest idx
            float best = -1e31f; int bi = 0;
            for (int i = 0; i < NE; i++)
                if (smm[i] > best) { best = smm[i]; bi = i; }
            smm[bi] = -1e32f;
            ids[k] = bi; wv[k] = ss[bi]; wsum += ss[bi];
        }
        float inv = SCALE / wsum;
        for (int k = 0; k < TOPK; k++) {
            int ee = ids[k];
            int pos = atomicAdd(&counts[ee], 1);
            tok_ids[ee * T_TOK + pos] = t;
            tok_w[ee * T_TOK + pos] = wv[k] * inv;
        }
    }
}

__global__ void k_scan(const int* __restrict__ counts, int* __restrict__ offs) {
    if (threadIdx.x == 0) {
        int o = 0;
        for (int e = 0; e < NE; e++) { offs[e] = o; o += counts[e]; }
    }
}

// ---------------- GEMM tile config ----------------
#define BM  128
#define BK  32
#define LDA 52    // bf16 elems; 104B rows: b64-aligned, conflict-light
#define LDB 44    // bf16 elems; 88B rows (B stored transposed [col][k])

// routed gate_up: act[slot, 0..I) = silu(g)*u*cw, 64 act cols per block
__global__ __launch_bounds__(256) void k_gemm1_routed(
    const float* __restrict__ wgu, const u16* __restrict__ xb,
    const int* __restrict__ counts, const int* __restrict__ offs,
    const int* __restrict__ tok_ids, const float* __restrict__ tok_w,
    u16* __restrict__ act) {
    const int nb = blockIdx.x, mt = blockIdx.y, e = blockIdx.z;
    const int ne = counts[e];
    if (mt * BM >= ne) return;
    const int base = offs[e];
    __shared__ u16 Al[BM * LDA];
    __shared__ u16 Bl[128 * LDB];
    __shared__ int tokl[BM];
    __shared__ float cwl[BM];
    const int tid = threadIdx.x, lane = tid & 63, wv = tid >> 6;
    const int wm = wv >> 1, wn = wv & 1;
    if (tid < BM) {
        int slot = mt * BM + tid;
        tokl[tid] = (slot < ne) ? tok_ids[e * T_TOK + slot] : 0;
        cwl[tid]  = (slot < ne) ? tok_w[e * T_TOK + slot] : 0.f;
    }
    __syncthreads();
    const f32x4 ZERO = {0.f, 0.f, 0.f, 0.f};
    f32x4 accg[4][2], accu[4][2];
#pragma unroll
    for (int mi = 0; mi < 4; mi++)
#pragma unroll
        for (int ni = 0; ni < 2; ni++) { accg[mi][ni] = ZERO; accu[mi][ni] = ZERO; }

    const int arow = tid >> 1, ahalf = tid & 1;
    const size_t atok = (size_t)tokl[arow];
    const int bc = tid & 127, bkq = tid >> 7;
    const int g0 = nb * 64;
    const int gcol = (bc < 64) ? (g0 + bc) : (ID + g0 + bc - 64);
    const float* bp0 = wgu + (size_t)e * HD * (2 * ID) + gcol;

    for (int kk = 0; kk < HD; kk += BK) {
        { // A stage: gathered token rows, bf16 copy
            const u16* s = xb + atok * HD + kk + ahalf * 16;
            const uint4* s4 = (const uint4*)s;
            union { uint4 q; u64 h[2]; } va, vb;
            va.q = s4[0]; vb.q = s4[1];
            u64* d = (u64*)&Al[arow * LDA + ahalf * 16];
            d[0] = va.h[0]; d[1] = va.h[1]; d[2] = vb.h[0]; d[3] = vb.h[1];
        }
        { // B stage: column-quad loads (lane-coalesced), transposed LDS write
#pragma unroll
            for (int p = 0; p < 4; p++) {
                int r0 = (p * 2 + bkq) * 4;
                const float* bp = bp0 + (size_t)(kk + r0) * (2 * ID);
                float f0 = bp[0];
                float f1 = bp[2 * ID];
                float f2 = bp[4 * ID];
                float f3 = bp[6 * ID];
                union { u16 u[4]; u64 ll; } pk;
                pk.u[0] = f2bf(f0); pk.u[1] = f2bf(f1);
                pk.u[2] = f2bf(f2); pk.u[3] = f2bf(f3);
                *(u64*)&Bl[bc * LDB + r0] = pk.ll;
            }
        }
        __syncthreads();
        bf16x8 af[4];
#pragma unroll
        for (int mi = 0; mi < 4; mi++) {
            int m = wm * 64 + mi * 16 + (lane & 15);
            af[mi] = ldfrag(&Al[m * LDA + 4 * (lane >> 4)]);
        }
#pragma unroll
        for (int ni = 0; ni < 2; ni++) {
            int cg = wn * 32 + ni * 16 + (lane & 15);
            bf16x8 bg = ldfrag(&Bl[cg * LDB + 4 * (lane >> 4)]);
            bf16x8 bu = ldfrag(&Bl[(64 + cg) * LDB + 4 * (lane >> 4)]);
#pragma unroll
            for (int mi = 0; mi < 4; mi++) {
                accg[mi][ni] = mfma16(af[mi], bg, accg[mi][ni]);
                accu[mi][ni] = mfma16(af[mi], bu, accu[mi][ni]);
            }
        }
        __syncthreads();
    }
    // epilogue: silu(g)*u*cw -> bf16 act (compact rows)
#pragma unroll
    for (int mi = 0; mi < 4; mi++) {
        int rl0 = wm * 64 + mi * 16 + 4 * (lane >> 4);
#pragma unroll
        for (int ni = 0; ni < 2; ni++) {
            int col = nb * 64 + wn * 32 + ni * 16 + (lane & 15);
#pragma unroll
            for (int j = 0; j < 4; j++) {
                int rl = rl0 + j, slot = mt * BM + rl;
                if (slot < ne) {
                    float g = accg[mi][ni][j], u = accu[mi][ni][j];
                    float v = g / (1.f + __expf(-g)) * u * cwl[rl];
                    act[(size_t)(base + slot) * ID + col] = f2bf(v);
                }
            }
        }
    }
}

// routed down: out[tok, col] += act @ w_down (atomic scatter-add)
__global__ __launch_bounds__(256) void k_gemm2_routed(
    const float* __restrict__ wd, const u16* __restrict__ act,
    const int* __restrict__ counts, const int* __restrict__ offs,
    const int* __restrict__ tok_ids, float* __restrict__ out) {
    const int nb = blockIdx.x, mt = blockIdx.y, e = blockIdx.z;
    const int ne = counts[e];
    if (mt * BM >= ne) return;
    const int base = offs[e];
    __shared__ u16 Al[BM * LDA];
    __shared__ u16 Bl[128 * LDB];
    __shared__ int tokl[BM];
    const int tid = threadIdx.x, lane = tid & 63, wv = tid >> 6;
    const int wm = wv >> 1, wn = wv & 1;
    if (tid < BM) {
        int slot = mt * BM + tid;
        tokl[tid] = (slot < ne) ? tok_ids[e * T_TOK + slot] : 0;
    }
    __syncthreads();
    const f32x4 ZERO = {0.f, 0.f, 0.f, 0.f};
    f32x4 acc[4][4];
#pragma unroll
    for (int mi = 0; mi < 4; mi++)
#pragma unroll
        for (int ni = 0; ni < 4; ni++) acc[mi][ni] = ZERO;

    const int arow = tid >> 1, ahalf = tid & 1;
    int srow = mt * BM + arow; if (srow >= ne) srow = ne - 1;   // clamp pad rows
    const size_t aro = (size_t)(base + srow);
    const int bc = tid & 127, bkq = tid >> 7;
    const float* bp0 = wd + (size_t)e * ID * HD + nb * 128 + bc;

    for (int kk = 0; kk < ID; kk += BK) {
        {
            const u16* s = act + aro * ID + kk + ahalf * 16;
            const uint4* s4 = (const uint4*)s;
            union { uint4 q; u64 h[2]; } va, vb;
            va.q = s4[0]; vb.q = s4[1];
            u64* d = (u64*)&Al[arow * LDA + ahalf * 16];
            d[0] = va.h[0]; d[1] = va.h[1]; d[2] = vb.h[0]; d[3] = vb.h[1];
        }
        {
#pragma unroll
            for (int p = 0; p < 4; p++) {
                int r0 = (p * 2 + bkq) * 4;
                const float* bp = bp0 + (size_t)(kk + r0) * HD;
                float f0 = bp[0];
                float f1 = bp[HD];
                float f2 = bp[2 * HD];
                float f3 = bp[3 * HD];
                union { u16 u[4]; u64 ll; } pk;
                pk.u[0] = f2bf(f0); pk.u[1] = f2bf(f1);
                pk.u[2] = f2bf(f2); pk.u[3] = f2bf(f3);
                *(u64*)&Bl[bc * LDB + r0] = pk.ll;
            }
        }
        __syncthreads();
        bf16x8 af[4];
#pragma unroll
        for (int mi = 0; mi < 4; mi++) {
            int m = wm * 64 + mi * 16 + (lane & 15);
            af[mi] = ldfrag(&Al[m * LDA + 4 * (lane >> 4)]);
        }
#pragma unroll
        for (int ni = 0; ni < 4; ni++) {
            int c = wn * 64 + ni * 16 + (lane & 15);
            bf16x8 bf = ldfrag(&Bl[c * LDB + 4 * (lane >> 4)]);
#pragma unroll
            for (int mi = 0; mi < 4; mi++)
                acc[mi][ni] = mfma16(af[mi], bf, acc[mi][ni]);
        }
        __syncthreads();
    }
#pragma unroll
    for (int mi = 0; mi < 4; mi++) {
        int rl0 = wm * 64 + mi * 16 + 4 * (lane >> 4);
#pragma unroll
        for (int ni = 0; ni < 4; ni++) {
            int col = nb * 128 + wn * 64 + ni * 16 + (lane & 15);
#pragma unroll
            for (int j = 0; j < 4; j++) {
                int rl = rl0 + j, slot = mt * BM + rl;
                if (slot < ne)
                    atomicAdd(&out[(size_t)tokl[rl] * HD + col], acc[mi][ni][j]);
            }
        }
    }
}

// shared gate_up: sact[t, 0..2048) = silu(g)*u
__global__ __launch_bounds__(256) void k_gemm1_shared(
    const float* __restrict__ wsgu, const u16* __restrict__ xb,
    u16* __restrict__ sact) {
    const int nb = blockIdx.x, mt = blockIdx.y;
    __shared__ u16 Al[BM * LDA];
    __shared__ u16 Bl[128 * LDB];
    const int tid = threadIdx.x, lane = tid & 63, wv = tid >> 6;
    const int wm = wv >> 1, wn = wv & 1;
    const f32x4 ZERO = {0.f, 0.f, 0.f, 0.f};
    f32x4 accg[4][2], accu[4][2];
#pragma unroll
    for (int mi = 0; mi < 4; mi++)
#pragma unroll
        for (int ni = 0; ni < 2; ni++) { accg[mi][ni] = ZERO; accu[mi][ni] = ZERO; }

    const int arow = tid >> 1, ahalf = tid & 1;
    const size_t aro = (size_t)(mt * BM + arow);
    const int bc = tid & 127, bkq = tid >> 7;
    const int NS = 2 * NSH * ID;   // 4096
    const int gcol = (bc < 64) ? (nb * 64 + bc) : (NSH * ID + nb * 64 + bc - 64);
    const float* bp0 = wsgu + gcol;

    for (int kk = 0; kk < HD; kk += BK) {
        {
            const u16* s = xb + aro * HD + kk + ahalf * 16;
            const uint4* s4 = (const uint4*)s;
            union { uint4 q; u64 h[2]; } va, vb;
            va.q = s4[0]; vb.q = s4[1];
            u64* d = (u64*)&Al[arow * LDA + ahalf * 16];
            d[0] = va.h[0]; d[1] = va.h[1]; d[2] = vb.h[0]; d[3] = vb.h[1];
        }
        {
#pragma unroll
            for (int p = 0; p < 4; p++) {
                int r0 = (p * 2 + bkq) * 4;
                const float* bp = bp0 + (size_t)(kk + r0) * NS;
                float f0 = bp[0];
                float f1 = bp[NS];
                float f2 = bp[2 * NS];
                float f3 = bp[3 * NS];
                union { u16 u[4]; u64 ll; } pk;
                pk.u[0] = f2bf(f0); pk.u[1] = f2bf(f1);
                pk.u[2] = f2bf(f2); pk.u[3] = f2bf(f3);
                *(u64*)&Bl[bc * LDB + r0] = pk.ll;
            }
        }
        __syncthreads();
        bf16x8 af[4];
#pragma unroll
        for (int mi = 0; mi < 4; mi++) {
            int m = wm * 64 + mi * 16 + (lane & 15);
            af[mi] = ldfrag(&Al[m * LDA + 4 * (lane >> 4)]);
        }
#pragma unroll
        for (int ni = 0; ni < 2; ni++) {
            int cg = wn * 32 + ni * 16 + (lane & 15);
            bf16x8 bg = ldfrag(&Bl[cg * LDB + 4 * (lane >> 4)]);
            bf16x8 bu = ldfrag(&Bl[(64 + cg) * LDB + 4 * (lane >> 4)]);
#pragma unroll
            for (int mi = 0; mi < 4; mi++) {
                accg[mi][ni] = mfma16(af[mi], bg, accg[mi][ni]);
                accu[mi][ni] = mfma16(af[mi], bu, accu[mi][ni]);
            }
        }
        __syncthreads();
    }
#pragma unroll
    for (int mi = 0; mi < 4; mi++) {
        int rl0 = wm * 64 + mi * 16 + 4 * (lane >> 4);
#pragma unroll
        for (int ni = 0; ni < 2; ni++) {
            int col = nb * 64 + wn * 32 + ni * 16 + (lane & 15);
#pragma unroll
            for (int j = 0; j < 4; j++) {
                int rl = rl0 + j;
                float g = accg[mi][ni][j], u = accu[mi][ni][j];
                float v = g / (1.f + __expf(-g)) * u;
                sact[(size_t)(mt * BM + rl) * (NSH * ID) + col] = f2bf(v);
            }
        }
    }
}

// shared down: out = sact @ w_sd  (plain store, initializes out)
__global__ __launch_bounds__(256) void k_gemm2_shared(
    const float* __restrict__ wsd, const u16* __restrict__ sact,
    float* __restrict__ out) {
    const int nb = blockIdx.x, mt = blockIdx.y;
    __shared__ u16 Al[BM * LDA];
    __shared__ u16 Bl[128 * LDB];
    const int tid = threadIdx.x, lane = tid & 63, wv = tid >> 6;
    const int wm = wv >> 1, wn = wv & 1;
    const f32x4 ZERO = {0.f, 0.f, 0.f, 0.f};
    f32x4 acc[4][4];
#pragma unroll
    for (int mi = 0; mi < 4; mi++)
#pragma unroll
        for (int ni = 0; ni < 4; ni++) acc[mi][ni] = ZERO;

    const int arow = tid >> 1, ahalf = tid & 1;
    const size_t aro = (size_t)(mt * BM + arow);
    const int bc = tid & 127, bkq = tid >> 7;
    const int KS = NSH * ID;   // 2048
    const float* bp0 = wsd + nb * 128 + bc;

    for (int kk = 0; kk < KS; kk += BK) {
        {
            const u16* s = sact + aro * KS + kk + ahalf * 16;
            const uint4* s4 = (const uint4*)s;
            union { uint4 q; u64 h[2]; } va, vb;
            va.q = s4[0]; vb.q = s4[1];
            u64* d = (u64*)&Al[arow * LDA + ahalf * 16];
            d[0] = va.h[0]; d[1] = va.h[1]; d[2] = vb.h[0]; d[3] = vb.h[1];
        }
        {
#pragma unroll
            for (int p = 0; p < 4; p++) {
                int r0 = (p * 2 + bkq) * 4;
                const float* bp = bp0 + (size_t)(kk + r0) * HD;
                float f0 = bp[0];
                float f1 = bp[HD];
                float f2 = bp[2 * HD];
                float f3 = bp[3 * HD];
                union { u16 u[4]; u64 ll; } pk;
                pk.u[0] = f2bf(f0); pk.u[1] = f2bf(f1);
                pk.u[2] = f2bf(f2); pk.u[3] = f2bf(f3);
                *(u64*)&Bl[bc * LDB + r0] = pk.ll;
            }
        }
        __syncthreads();
        bf16x8 af[4];
#pragma unroll
        for (int mi = 0; mi < 4; mi++) {
            int m = wm * 64 + mi * 16 + (lane & 15);
            af[mi] = ldfrag(&Al[m * LDA + 4 * (lane >> 4)]);
        }
#pragma unroll
        for (int ni = 0; ni < 4; ni++) {
            int c = wn * 64 + ni * 16 + (lane & 15);
            bf16x8 bf = ldfrag(&Bl[c * LDB + 4 * (lane >> 4)]);
#pragma unroll
            for (int mi = 0; mi < 4; mi++)
                acc[mi][ni] = mfma16(af[mi], bf, acc[mi][ni]);
        }
        __syncthreads();
    }
#pragma unroll
    for (int mi = 0; mi < 4; mi++) {
        int rl0 = wm * 64 + mi * 16 + 4 * (lane >> 4);
#pragma unroll
        for (int ni = 0; ni < 4; ni++) {
            int col = nb * 128 + wn * 64 + ni * 16 + (lane & 15);
#pragma unroll
            for (int j = 0; j < 4; j++) {
                int rl = rl0 + j;
                out[(size_t)(mt * BM + rl) * HD + col] = acc[mi][ni][j];
            }
        }
    }
}

// ---------------- launcher ----------------
extern "C" void kernel_launch(void* const* d_in, const int* in_sizes, int n_in,
                              void* d_out, int out_size, void* d_ws, size_t ws_size,
                              hipStream_t stream) {
    const float* x    = (const float*)d_in[0];
    const float* gw   = (const float*)d_in[1];
    const float* gb   = (const float*)d_in[2];
    const float* wgu  = (const float*)d_in[3];
    const float* wd   = (const float*)d_in[4];
    const float* wsgu = (const float*)d_in[5];
    const float* wsd  = (const float*)d_in[6];
    float* out = (float*)d_out;

    char* wsb = (char*)d_ws;
    int*   counts  = (int*)(wsb);                    // 32 ints
    int*   offs    = (int*)(wsb + 128);              // 32 ints
    int*   tok_ids = (int*)(wsb + 256);              // 32*512 ints
    float* tok_w   = (float*)(wsb + 65792);          // 32*512 floats
    u16*   xb      = (u16*)(wsb + 131584);           // 512*2048 bf16
    u16*   act     = (u16*)(wsb + 2228736);          // 4096*1024 bf16
    u16*   sact    = (u16*)(wsb + 10617344);         // 512*2048 bf16
    // total ws use: ~12.7 MB

    hipMemsetAsync(counts, 0, 128, stream);
    k_xconv<<<dim3((T_TOK * HD) / (256 * 8)), 256, 0, stream>>>(x, xb);
    k_route<<<dim3(T_TOK), 64, 0, stream>>>(x, gw, gb, counts, tok_ids, tok_w);
    k_scan<<<dim3(1), 64, 0, stream>>>(counts, offs);
    k_gemm1_routed<<<dim3(ID / 64, 4, NE), 256, 0, stream>>>(
        wgu, xb, counts, offs, tok_ids, tok_w, act);
    k_gemm1_shared<<<dim3((NSH * ID) / 64, 4), 256, 0, stream>>>(wsgu, xb, sact);
    k_gemm2_shared<<<dim3(HD / 128, 4), 256, 0, stream>>>(wsd, sact, out);
    k_gemm2_routed<<<dim3(HD / 128, 4, NE), 256, 0, stream>>>(
        wd, act, counts, offs, tok_ids, out);
}